// Round 8
// baseline (170.625 us; speedup 1.0000x reference)
//
#include <hip/hip_runtime.h>

// Problem constants (fixed by setup_inputs)
constexpr int BATCH = 8;
constexpr int NPB   = 1 << 20;       // N per batch
constexpr int BS    = 128;           // block_size
constexpr int NB    = NPB / BS;      // 8192 node-blocks per batch
constexpr int NBLK  = BATCH * NB;    // 65536 total node-blocks
constexpr int MAXKV = 32;

#define GRAPH_WEIGHT 0.3f

// Phase 1: persistent waves, software-pipelined streaming.
constexpr int P1_WGS   = 512;                 // 2048 waves total
constexpr int P1_ITERS = 8;                   // 4 blocks/wave/iter * 8 = 32 blocks/wave
constexpr int P2_WGS   = 2048;                // 32 node-blocks per wg

// Workspace layout (floats). Every slot fully overwritten each call ->
// no memset dispatch, no atomics, no fences (kernel boundaries provide
// cross-XCD visibility; R6 showed in-kernel fences cost ~42us).
constexpr int WS_BSC = 0;                    // float2[NBLK] {sum keep*p, keep cnt}
constexpr int WS_QUP = 2 * NBLK;             // float4[NBLK] {q, sum u*p, sum u*p^2, 0}
constexpr int WS_SUP = WS_QUP + 4 * NBLK;    // float2[P1_WGS] {sup_sum, sup_cnt}
constexpr int WS_P2  = WS_SUP + 2 * P1_WGS;  // float4[P2_WGS] {L, C, U, 0}

typedef float v4f __attribute__((ext_vector_type(4)));
typedef int   v4i __attribute__((ext_vector_type(4)));

// ---------------- Phase 1: persistent pipelined streaming pass ----------------
// Each wave owns 32 consecutive node-blocks, processed as 8 iterations of
// 4 blocks (lanes 16g..16g+15 own block g; each lane 2 float4-chunks/array).
// Register double-buffer: iteration i+1's 8 nt loads are issued BEFORE
// computing iteration i, so the read queue never fully drains (the one-shot
// waves of R4-R7 drained vmcnt(0) once per wave life — this is the lever
// none of them pulled).
__global__ __launch_bounds__(256) void k_phase1(const v4f* __restrict__ lg4,
                                                const v4f* __restrict__ tg4,
                                                const v4i* __restrict__ sm4,
                                                const v4i* __restrict__ im4,
                                                float* __restrict__ ws)
{
    const int lane = threadIdx.x & 63;
    const int wv   = threadIdx.x >> 6;               // wave in wg (0..3)
    const int W    = (blockIdx.x << 2) + wv;         // global wave id (0..2047)
    const int grp  = lane >> 4;                      // block group (0..3)
    const int sub  = lane & 15;                      // sub-lane in group
    const int cb   = (W * 32 + grp) * 32 + sub;      // base chunk; iter stride 128

    v4f xb[2][2], tb[2][2];
    v4i sb[2][2], gb[2][2];

    auto load_iter = [&](int buf, int it) {
        const int c = cb + it * 128;
        xb[buf][0] = __builtin_nontemporal_load(lg4 + c);
        xb[buf][1] = __builtin_nontemporal_load(lg4 + c + 16);
        tb[buf][0] = __builtin_nontemporal_load(tg4 + c);
        tb[buf][1] = __builtin_nontemporal_load(tg4 + c + 16);
        sb[buf][0] = __builtin_nontemporal_load(sm4 + c);
        sb[buf][1] = __builtin_nontemporal_load(sm4 + c + 16);
        gb[buf][0] = __builtin_nontemporal_load(im4 + c);
        gb[buf][1] = __builtin_nontemporal_load(im4 + c + 16);
    };

    float sup_sum = 0.f, sup_cnt = 0.f;
    load_iter(0, 0);

#pragma unroll
    for (int it = 0; it < P1_ITERS; ++it) {
        if (it + 1 < P1_ITERS) load_iter((it + 1) & 1, it + 1);  // prefetch
        const int buf = it & 1;

        float bsum = 0.f, bcnt = 0.f, q = 0.f, up = 0.f, up2 = 0.f;
#pragma unroll
        for (int h = 0; h < 2; ++h) {
#pragma unroll
            for (int k = 0; k < 4; ++k) {
                const float x = xb[buf][h][k], t = tb[buf][h][k];
                const bool s = (sb[buf][h][k] != 0);
                const bool g = (gb[buf][h][k] != 0);

                const float ax  = fabsf(x);
                const float e   = __expf(-ax);          // (0,1]
                const float lp  = __logf(1.f + e);      // log1p(exp(-|x|))
                const float per = fmaxf(x, 0.f) - x * t + lp;
                const float inv = 1.f / (1.f + e);
                const float p   = (x >= 0.f) ? inv : e * inv;   // sigmoid(x)

                if (s) { sup_sum += per; sup_cnt += 1.f; }
                if (!g) { bsum += p; bcnt += 1.f; }
                if (!g && !s) { q += 1.f; up += p; up2 += p * p; }
            }
        }

        // block stats: reduce over the 16-lane group (d = 8,4,2,1)
#pragma unroll
        for (int d = 8; d >= 1; d >>= 1) {
            bsum += __shfl_xor(bsum, d);
            bcnt += __shfl_xor(bcnt, d);
            q    += __shfl_xor(q, d);
            up   += __shfl_xor(up, d);
            up2  += __shfl_xor(up2, d);
        }
        if (sub == 0) {
            const int blk = W * 32 + it * 4 + grp;     // node-block id
            *reinterpret_cast<float2*>(ws + WS_BSC + 2 * blk) = make_float2(bsum, bcnt);
            *reinterpret_cast<float4*>(ws + WS_QUP + 4 * blk) = make_float4(q, up, up2, 0.f);
        }
    }

    // sup terms: full-wave reduction, one plain float2 store per workgroup
#pragma unroll
    for (int d = 32; d >= 1; d >>= 1) {
        sup_sum += __shfl_xor(sup_sum, d);
        sup_cnt += __shfl_xor(sup_cnt, d);
    }
    __shared__ float lsup[4][2];
    if (lane == 0) { lsup[wv][0] = sup_sum; lsup[wv][1] = sup_cnt; }
    __syncthreads();
    if (threadIdx.x == 0) {
        const float a = lsup[0][0] + lsup[1][0] + lsup[2][0] + lsup[3][0];
        const float b = lsup[0][1] + lsup[1][1] + lsup[2][1] + lsup[3][1];
        *reinterpret_cast<float2*>(ws + WS_SUP + 2 * blockIdx.x) = make_float2(a, b);
    }
}

// ---------------- Phase 2: neighbor gather, 32 node-blocks per wg ----------
// (R5 version — proven <6us.) Each 32-lane half-wave handles 4 consecutive
// node-blocks; one plain float4 partial per wg. No atomics, no fences.
__global__ __launch_bounds__(256) void k_phase2(const int* __restrict__ kvi,
                                                const int* __restrict__ kvn,
                                                float* __restrict__ ws)
{
    const int hw     = threadIdx.x >> 5;        // half-wave 0..7
    const int lane32 = threadIdx.x & 31;
    const int h0     = blockIdx.x * 32 + hw * 4;          // first of 4 blocks
    const int bbase  = (blockIdx.x >> 8) << 13;           // batch * NB

    const v4i nkv4 = *reinterpret_cast<const v4i*>(kvn + h0);

    int idxs[4];
#pragma unroll
    for (int j = 0; j < 4; ++j)
        idxs[j] = __builtin_nontemporal_load(kvi + (size_t)(h0 + j) * MAXKV + lane32);

    float gsv[4], gcv[4];
#pragma unroll
    for (int j = 0; j < 4; ++j) {
        float gs = 0.f, gc = 0.f;
        if (lane32 < nkv4[j]) {
            const float2 v = *reinterpret_cast<const float2*>(ws + WS_BSC + 2 * (bbase + idxs[j]));
            gs = v.x; gc = v.y;
        }
#pragma unroll
        for (int d = 16; d >= 1; d >>= 1) {
            gs += __shfl_xor(gs, d);
            gc += __shfl_xor(gc, d);
        }
        gsv[j] = gs; gcv[j] = gc;   // every lane now holds block j's totals
    }

    // lanes 0..3: finalize block h0+lane (coalesced 64B QUP read)
    float L = 0.f, C = 0.f, U = 0.f;
    if (lane32 < 4) {
        const int k = lane32;
        const float4 quv = *reinterpret_cast<const float4*>(ws + WS_QUP + 4 * (h0 + k));
        const float q = quv.x, up = quv.y, up2 = quv.z;
        const float gs = gsv[k], gc = gcv[k];
        const float m  = gs / fmaxf(gc, 1.f);
        const bool  vb = (q > 0.f) && (nkv4[k] > 0) && (gc > 0.f);
        const float sq = up2 - 2.f * m * up + m * m * q;  // sum_u (p-m)^2
        L = vb ? sq : 0.f;
        C = vb ? q  : 0.f;
        U = q;                                   // unconditional: uncertain.any()
    }
#pragma unroll
    for (int d = 2; d >= 1; d >>= 1) {
        L += __shfl_xor(L, d);
        C += __shfl_xor(C, d);
        U += __shfl_xor(U, d);
    }

    __shared__ float l2s[8][3];
    if (lane32 == 0) { l2s[hw][0] = L; l2s[hw][1] = C; l2s[hw][2] = U; }
    __syncthreads();
    if (threadIdx.x == 0) {
        float Ls = 0.f, Cs = 0.f, Us = 0.f;
#pragma unroll
        for (int j = 0; j < 8; ++j) { Ls += l2s[j][0]; Cs += l2s[j][1]; Us += l2s[j][2]; }
        *reinterpret_cast<float4*>(ws + WS_P2 + 4 * blockIdx.x) = make_float4(Ls, Cs, Us, 0.f);
    }
}

// ---------------- Phase 3: final reduce (one 512-thread workgroup) ----------
__global__ __launch_bounds__(512) void k_phase3(const float* __restrict__ ws,
                                                float* __restrict__ out)
{
    const int tid  = threadIdx.x;          // 0..511
    const int lane = tid & 63;
    const int w    = tid >> 6;             // wave 0..7

    __shared__ float lsup[8][2];
    __shared__ float lfin[8][3];

    // sup partials: 512 float2 = 256 float4 {s,c,s,c}; threads 0..255
    const v4f* supf4 = reinterpret_cast<const v4f*>(ws + WS_SUP);
    float ss = 0.f, sc = 0.f;
    if (tid < 256) {
        const v4f v = supf4[tid];
        ss = v.x + v.z; sc = v.y + v.w;
    }
#pragma unroll
    for (int d = 32; d >= 1; d >>= 1) { ss += __shfl_xor(ss, d); sc += __shfl_xor(sc, d); }
    if (lane == 0) { lsup[w][0] = ss; lsup[w][1] = sc; }

    // p2 partials: wave w handles batch w: slots [w*256, w*256+256), 4/lane
    const v4f* p2f4 = reinterpret_cast<const v4f*>(ws + WS_P2);
    float L = 0.f, C = 0.f, U = 0.f;
#pragma unroll
    for (int j = 0; j < 4; ++j) {
        const v4f v = p2f4[w * 256 + lane * 4 + j];
        L += v.x; C += v.y; U += v.z;
    }
#pragma unroll
    for (int d = 32; d >= 1; d >>= 1) {
        L += __shfl_xor(L, d);
        C += __shfl_xor(C, d);
        U += __shfl_xor(U, d);
    }
    if (lane == 0) { lfin[w][0] = L; lfin[w][1] = C; lfin[w][2] = U; }
    __syncthreads();

    if (tid == 0) {
        float ssum = 0.f, scn = 0.f;
#pragma unroll
        for (int j = 0; j < 8; ++j) { ssum += lsup[j][0]; scn += lsup[j][1]; }
        float per = 0.f, nv = 0.f, uc = 0.f;
#pragma unroll
        for (int b = 0; b < 8; ++b) {
            const float l = lfin[b][0], c = lfin[b][1], u = lfin[b][2];
            if (c > 0.f) { per += l / fmaxf(c, 1.f); nv += 1.f; }
            uc += u;
        }
        const float loss_sup = (scn > 0.f) ? ssum / fmaxf(scn, 1.f) : 0.f;
        float lgr = per / fmaxf(nv, 1.f);
        if (!(uc > 0.f)) lgr = 0.f;
        out[0] = loss_sup + GRAPH_WEIGHT * lgr;
    }
}

extern "C" void kernel_launch(void* const* d_in, const int* in_sizes, int n_in,
                              void* d_out, int out_size, void* d_ws, size_t ws_size,
                              hipStream_t stream) {
    const v4f* lg4 = (const v4f*)d_in[0];  // logits  [B,N,1]
    const v4f* tg4 = (const v4f*)d_in[1];  // targets [B,N]
    const v4i* sm4 = (const v4i*)d_in[2];  // sup_mask (int32)
    const v4i* im4 = (const v4i*)d_in[3];  // ignore_mask (int32)
    const int* kvi = (const int*)d_in[4];  // kv_indices [B,NB,MAXKV]
    const int* kvn = (const int*)d_in[5];  // kv_num_blocks [B,NB]
    float* ws  = (float*)d_ws;
    float* out = (float*)d_out;

    k_phase1<<<P1_WGS, 256, 0, stream>>>(lg4, tg4, sm4, im4, ws);
    k_phase2<<<P2_WGS, 256, 0, stream>>>(kvi, kvn, ws);
    k_phase3<<<1, 512, 0, stream>>>(ws, out);
}

// Round 9
// 164.329 us; speedup vs baseline: 1.0383x; 1.0383x over previous
//
#include <hip/hip_runtime.h>

// Problem constants (fixed by setup_inputs)
constexpr int BATCH = 8;
constexpr int NPB   = 1 << 20;       // N per batch
constexpr int BS    = 128;           // block_size
constexpr int NB    = NPB / BS;      // 8192 node-blocks per batch
constexpr int NBLK  = BATCH * NB;    // 65536 total node-blocks
constexpr int MAXKV = 32;

#define GRAPH_WEIGHT 0.3f

constexpr int P1_WGS = (BATCH * NPB) / (256 * 4);   // 8192 wgs, 4 elems/thread
constexpr int P2_WGS = 2048;                         // 32 node-blocks per wg

// Workspace layout (floats). Every slot fully overwritten each call ->
// no memset dispatch, no atomics, no fences (kernel boundaries provide
// cross-XCD visibility; R6 showed in-kernel fences cost ~42us).
constexpr int WS_BSC = 0;                    // float2[NBLK] {sum keep*p, keep cnt}
constexpr int WS_QUP = 2 * NBLK;             // float4[NBLK] {q, sum u*p, sum u*p^2, 0}
constexpr int WS_SUP = WS_QUP + 4 * NBLK;    // float2[P1_WGS] {sup_sum, sup_cnt}
constexpr int WS_P2  = WS_SUP + 2 * P1_WGS;  // float4[P2_WGS] {L, C, U, 0}

typedef float v4f __attribute__((ext_vector_type(4)));
typedef int   v4i __attribute__((ext_vector_type(4)));

// ---------------- Phase 1: max-TLP one-shot streaming pass ----------------
// 4 elems/thread (one nt float4/int4 per stream), 32768 waves, VGPR capped by
// __launch_bounds__(256,8) for 8 waves/SIMD. R8 proved wave-level parallelism
// IS the pipeline on CDNA4; this is the max-TLP point of the one-shot+nt
// family (R4=8/t, R5=16/t both ~4.2 TB/s; R1 ran 4/t pre-nt at 2.85 TB/s).
// One 128-elem node-block = one 32-lane half-wave (5-stage xor reduce).
__global__ __launch_bounds__(256, 8) void k_phase1(const v4f* __restrict__ lg4,
                                                   const v4f* __restrict__ tg4,
                                                   const v4i* __restrict__ sm4,
                                                   const v4i* __restrict__ im4,
                                                   float* __restrict__ ws)
{
    const int tid = blockIdx.x * 256 + threadIdx.x;   // == float4-chunk index

    const v4f x4 = __builtin_nontemporal_load(lg4 + tid);
    const v4f t4 = __builtin_nontemporal_load(tg4 + tid);
    const v4i s4 = __builtin_nontemporal_load(sm4 + tid);
    const v4i g4 = __builtin_nontemporal_load(im4 + tid);

    float sup_sum = 0.f, sup_cnt = 0.f;
    float bsum = 0.f, bcnt = 0.f, q = 0.f, up = 0.f, up2 = 0.f;

#pragma unroll
    for (int k = 0; k < 4; ++k) {
        const float x = x4[k], t = t4[k];
        const bool s = (s4[k] != 0);
        const bool g = (g4[k] != 0);

        const float ax  = fabsf(x);
        const float e   = __expf(-ax);          // (0,1]
        const float lp  = __logf(1.f + e);      // log1p(exp(-|x|))
        const float per = fmaxf(x, 0.f) - x * t + lp;
        const float inv = 1.f / (1.f + e);
        const float p   = (x >= 0.f) ? inv : e * inv;   // sigmoid(x)

        if (s) { sup_sum += per; sup_cnt += 1.f; }
        if (!g) { bsum += p; bcnt += 1.f; }
        if (!g && !s) { q += 1.f; up += p; up2 += p * p; }
    }

    // block stats: one 128-elem block per 32-lane half-wave (d = 16..1)
#pragma unroll
    for (int d = 16; d >= 1; d >>= 1) {
        bsum += __shfl_xor(bsum, d);
        bcnt += __shfl_xor(bcnt, d);
        q    += __shfl_xor(q, d);
        up   += __shfl_xor(up, d);
        up2  += __shfl_xor(up2, d);
    }
    if ((threadIdx.x & 31) == 0) {
        const int blk = tid >> 5;                 // node-block id
        *reinterpret_cast<float2*>(ws + WS_BSC + 2 * blk) = make_float2(bsum, bcnt);
        *reinterpret_cast<float4*>(ws + WS_QUP + 4 * blk) = make_float4(q, up, up2, 0.f);
    }

    // sup terms: full-wave reduction, one plain float2 store per workgroup
#pragma unroll
    for (int d = 32; d >= 1; d >>= 1) {
        sup_sum += __shfl_xor(sup_sum, d);
        sup_cnt += __shfl_xor(sup_cnt, d);
    }
    __shared__ float lsup[4][2];
    const int lane = threadIdx.x & 63;
    const int w    = threadIdx.x >> 6;
    if (lane == 0) { lsup[w][0] = sup_sum; lsup[w][1] = sup_cnt; }
    __syncthreads();
    if (threadIdx.x == 0) {
        const float a = lsup[0][0] + lsup[1][0] + lsup[2][0] + lsup[3][0];
        const float b = lsup[0][1] + lsup[1][1] + lsup[2][1] + lsup[3][1];
        *reinterpret_cast<float2*>(ws + WS_SUP + 2 * blockIdx.x) = make_float2(a, b);
    }
}

// ---------------- Phase 2: neighbor gather, 32 node-blocks per wg ----------
// (R5 version — proven fast.) Each 32-lane half-wave handles 4 consecutive
// node-blocks; one plain float4 partial per wg. No atomics, no fences.
__global__ __launch_bounds__(256) void k_phase2(const int* __restrict__ kvi,
                                                const int* __restrict__ kvn,
                                                float* __restrict__ ws)
{
    const int hw     = threadIdx.x >> 5;        // half-wave 0..7
    const int lane32 = threadIdx.x & 31;
    const int h0     = blockIdx.x * 32 + hw * 4;          // first of 4 blocks
    const int bbase  = (blockIdx.x >> 8) << 13;           // batch * NB

    const v4i nkv4 = *reinterpret_cast<const v4i*>(kvn + h0);

    int idxs[4];
#pragma unroll
    for (int j = 0; j < 4; ++j)
        idxs[j] = __builtin_nontemporal_load(kvi + (size_t)(h0 + j) * MAXKV + lane32);

    float gsv[4], gcv[4];
#pragma unroll
    for (int j = 0; j < 4; ++j) {
        float gs = 0.f, gc = 0.f;
        if (lane32 < nkv4[j]) {
            const float2 v = *reinterpret_cast<const float2*>(ws + WS_BSC + 2 * (bbase + idxs[j]));
            gs = v.x; gc = v.y;
        }
#pragma unroll
        for (int d = 16; d >= 1; d >>= 1) {
            gs += __shfl_xor(gs, d);
            gc += __shfl_xor(gc, d);
        }
        gsv[j] = gs; gcv[j] = gc;   // every lane now holds block j's totals
    }

    // lanes 0..3: finalize block h0+lane (coalesced 64B QUP read)
    float L = 0.f, C = 0.f, U = 0.f;
    if (lane32 < 4) {
        const int k = lane32;
        const float4 quv = *reinterpret_cast<const float4*>(ws + WS_QUP + 4 * (h0 + k));
        const float q = quv.x, up = quv.y, up2 = quv.z;
        const float gs = gsv[k], gc = gcv[k];
        const float m  = gs / fmaxf(gc, 1.f);
        const bool  vb = (q > 0.f) && (nkv4[k] > 0) && (gc > 0.f);
        const float sq = up2 - 2.f * m * up + m * m * q;  // sum_u (p-m)^2
        L = vb ? sq : 0.f;
        C = vb ? q  : 0.f;
        U = q;                                   // unconditional: uncertain.any()
    }
#pragma unroll
    for (int d = 2; d >= 1; d >>= 1) {
        L += __shfl_xor(L, d);
        C += __shfl_xor(C, d);
        U += __shfl_xor(U, d);
    }

    __shared__ float l2s[8][3];
    if (lane32 == 0) { l2s[hw][0] = L; l2s[hw][1] = C; l2s[hw][2] = U; }
    __syncthreads();
    if (threadIdx.x == 0) {
        float Ls = 0.f, Cs = 0.f, Us = 0.f;
#pragma unroll
        for (int j = 0; j < 8; ++j) { Ls += l2s[j][0]; Cs += l2s[j][1]; Us += l2s[j][2]; }
        *reinterpret_cast<float4*>(ws + WS_P2 + 4 * blockIdx.x) = make_float4(Ls, Cs, Us, 0.f);
    }
}

// ---------------- Phase 3: final reduce (one 512-thread workgroup) ----------
__global__ __launch_bounds__(512) void k_phase3(const float* __restrict__ ws,
                                                float* __restrict__ out)
{
    const int tid  = threadIdx.x;          // 0..511
    const int lane = tid & 63;
    const int w    = tid >> 6;             // wave 0..7

    __shared__ float lsup[8][2];
    __shared__ float lfin[8][3];

    // sup partials: 8192 float2 = 4096 float4 {s,c,s,c}; 8 float4/thread
    const v4f* supf4 = reinterpret_cast<const v4f*>(ws + WS_SUP);
    float ss = 0.f, sc = 0.f;
#pragma unroll
    for (int j = 0; j < 8; ++j) {
        const v4f v = supf4[tid * 8 + j];
        ss += v.x + v.z; sc += v.y + v.w;
    }
#pragma unroll
    for (int d = 32; d >= 1; d >>= 1) { ss += __shfl_xor(ss, d); sc += __shfl_xor(sc, d); }
    if (lane == 0) { lsup[w][0] = ss; lsup[w][1] = sc; }

    // p2 partials: wave w handles batch w: slots [w*256, w*256+256), 4/lane
    const v4f* p2f4 = reinterpret_cast<const v4f*>(ws + WS_P2);
    float L = 0.f, C = 0.f, U = 0.f;
#pragma unroll
    for (int j = 0; j < 4; ++j) {
        const v4f v = p2f4[w * 256 + lane * 4 + j];
        L += v.x; C += v.y; U += v.z;
    }
#pragma unroll
    for (int d = 32; d >= 1; d >>= 1) {
        L += __shfl_xor(L, d);
        C += __shfl_xor(C, d);
        U += __shfl_xor(U, d);
    }
    if (lane == 0) { lfin[w][0] = L; lfin[w][1] = C; lfin[w][2] = U; }
    __syncthreads();

    if (tid == 0) {
        float ssum = 0.f, scn = 0.f;
#pragma unroll
        for (int j = 0; j < 8; ++j) { ssum += lsup[j][0]; scn += lsup[j][1]; }
        float per = 0.f, nv = 0.f, uc = 0.f;
#pragma unroll
        for (int b = 0; b < 8; ++b) {
            const float l = lfin[b][0], c = lfin[b][1], u = lfin[b][2];
            if (c > 0.f) { per += l / fmaxf(c, 1.f); nv += 1.f; }
            uc += u;
        }
        const float loss_sup = (scn > 0.f) ? ssum / fmaxf(scn, 1.f) : 0.f;
        float lgr = per / fmaxf(nv, 1.f);
        if (!(uc > 0.f)) lgr = 0.f;
        out[0] = loss_sup + GRAPH_WEIGHT * lgr;
    }
}

extern "C" void kernel_launch(void* const* d_in, const int* in_sizes, int n_in,
                              void* d_out, int out_size, void* d_ws, size_t ws_size,
                              hipStream_t stream) {
    const v4f* lg4 = (const v4f*)d_in[0];  // logits  [B,N,1]
    const v4f* tg4 = (const v4f*)d_in[1];  // targets [B,N]
    const v4i* sm4 = (const v4i*)d_in[2];  // sup_mask (int32)
    const v4i* im4 = (const v4i*)d_in[3];  // ignore_mask (int32)
    const int* kvi = (const int*)d_in[4];  // kv_indices [B,NB,MAXKV]
    const int* kvn = (const int*)d_in[5];  // kv_num_blocks [B,NB]
    float* ws  = (float*)d_ws;
    float* out = (float*)d_out;

    k_phase1<<<P1_WGS, 256, 0, stream>>>(lg4, tg4, sm4, im4, ws);
    k_phase2<<<P2_WGS, 256, 0, stream>>>(kvi, kvn, ws);
    k_phase3<<<1, 512, 0, stream>>>(ws, out);
}